// Round 1
// baseline (443.552 us; speedup 1.0000x reference)
//
#include <hip/hip_runtime.h>

// ODE sampler (VP-SDE probability-flow, RK4, T=50) for B=2048, D=16, H=256.
// Key math: trace of Jacobian computed analytically:
//   tr(J) = -0.5*beta*(D + sum_k (1-h_k^2)*c_k),  c_k = sum_i W1[i,k]*W2[k,i]
// so no JVPs are needed. One persistent kernel runs all 49 RK4 steps.
//
// Layout: 256 blocks x 256 threads, S=8 samples per block.
//   Phase 1 (per F-eval): thread t = hidden col k. W1 column in 16 VGPRs,
//     x-eval point read from LDS (wave-uniform broadcast). Writes h and
//     g=(1-h^2)*c_k to LDS.
//   Phase 2: thread t = (s, i, c2): sample s=t>>5, out dim i=(t>>1)&15,
//     k-half c2=t&1. 128-length dot from LDS float4 streams; score pair
//     combined with one shfl_xor; trace via 5-level butterfly over the
//     32 lanes of a sample.

#define Bn 2048
#define Dn 16
#define Hn 256
#define Tn 50
#define Sn 8
#define BLK 256
#define HP (Hn + 4)   // pad LDS rows to break power-of-2 strides

__global__ __launch_bounds__(BLK) void ode_kernel(
    const float* __restrict__ x_in,   // [B][D]
    const float* __restrict__ W1,     // [D][H]
    const float* __restrict__ b1v,    // [H]
    const float* __restrict__ wtv,    // [H]
    const float* __restrict__ W2,     // [H][D]
    const float* __restrict__ b2v,    // [D]
    float* __restrict__ out)          // xf[B*D] | ldjf[B] | xt[T*B*D]
{
    __shared__ __align__(16) float w2t[Dn][HP];   // W2 transposed
    __shared__ __align__(16) float h_s[Sn][HP];   // activations
    __shared__ __align__(16) float g_s[Sn][HP];   // (1-h^2)*c_k
    __shared__ __align__(16) float xe[Sn][Dn];    // current eval point

    const int t      = threadIdx.x;
    const int kcol   = t;             // phase-1 hidden column
    const int s      = t >> 5;        // phase-2 sample within block
    const int lane32 = t & 31;
    const int i      = lane32 >> 1;   // phase-2 output dim
    const int c2     = t & 1;         // phase-2 k-half

    // ---- one-time init: weights into registers / LDS ----
    float w1c[16];
    #pragma unroll
    for (int ii = 0; ii < 16; ++ii) w1c[ii] = W1[ii * Hn + kcol];

    const float4* w2row = (const float4*)(W2 + kcol * Dn);
    float4 r0 = w2row[0], r1 = w2row[1], r2 = w2row[2], r3 = w2row[3];
    float w2r[16] = { r0.x, r0.y, r0.z, r0.w, r1.x, r1.y, r1.z, r1.w,
                      r2.x, r2.y, r2.z, r2.w, r3.x, r3.y, r3.z, r3.w };

    float ck = 0.f;
    #pragma unroll
    for (int ii = 0; ii < 16; ++ii) ck = fmaf(w1c[ii], w2r[ii], ck);

    #pragma unroll
    for (int ii = 0; ii < 16; ++ii) w2t[ii][kcol] = w2r[ii];

    const float b1k = b1v[kcol];
    const float wtk = wtv[kcol];
    const float b2i = b2v[i];

    const int gs = blockIdx.x * Sn + s;          // global sample id
    float x   = x_in[gs * Dn + i];               // state component (s,i)
    float ldj = 0.f;

    float* xf_out  = out;
    float* ldj_out = out + (size_t)Bn * Dn;
    float* xt_out  = out + (size_t)Bn * Dn + Bn;

    if (c2 == 0) xt_out[gs * Dn + i] = x;        // xt[0] = initial x

    __syncthreads();                             // w2t ready

    auto Feval = [&](float xev, float tt, float& dx, float& dtr) {
        xe[s][i] = xev;                          // both c2 lanes write same value
        __syncthreads();

        // ---- phase 1: u_k, h_k, g_k for all Sn samples ----
        const float pre = fmaf(tt, wtk, b1k);
        #pragma unroll
        for (int s2 = 0; s2 < Sn; ++s2) {
            const float4* xr = (const float4*)(&xe[s2][0]);   // uniform addr: broadcast
            float4 x0 = xr[0], x1 = xr[1], x2 = xr[2], x3 = xr[3];
            float u = pre;
            u = fmaf(x0.x, w1c[0],  u); u = fmaf(x0.y, w1c[1],  u);
            u = fmaf(x0.z, w1c[2],  u); u = fmaf(x0.w, w1c[3],  u);
            u = fmaf(x1.x, w1c[4],  u); u = fmaf(x1.y, w1c[5],  u);
            u = fmaf(x1.z, w1c[6],  u); u = fmaf(x1.w, w1c[7],  u);
            u = fmaf(x2.x, w1c[8],  u); u = fmaf(x2.y, w1c[9],  u);
            u = fmaf(x2.z, w1c[10], u); u = fmaf(x2.w, w1c[11], u);
            u = fmaf(x3.x, w1c[12], u); u = fmaf(x3.y, w1c[13], u);
            u = fmaf(x3.z, w1c[14], u); u = fmaf(x3.w, w1c[15], u);
            // tanh(u) = 1 - 2/(e^{2u}+1); clamp avoids overflow, tanh saturated anyway
            float a  = fminf(fmaxf(u, -9.f), 9.f);
            float e  = __expf(2.f * a);
            float hv = 1.f - 2.f * __builtin_amdgcn_rcpf(e + 1.f);
            h_s[s2][kcol] = hv;
            g_s[s2][kcol] = (1.f - hv * hv) * ck;
        }
        __syncthreads();

        // ---- phase 2: score + trace, RK stage derivative ----
        const float4* hp = (const float4*)(&h_s[s][c2 * 128]);
        const float4* wp = (const float4*)(&w2t[i][c2 * 128]);
        float a0 = 0.f, a1 = 0.f, a2 = 0.f, a3 = 0.f;
        #pragma unroll 8
        for (int m = 0; m < 32; ++m) {
            float4 hv = hp[m], wv = wp[m];
            a0 = fmaf(hv.x, wv.x, a0);
            a1 = fmaf(hv.y, wv.y, a1);
            a2 = fmaf(hv.z, wv.z, a2);
            a3 = fmaf(hv.w, wv.w, a3);
        }
        float sc = (a0 + a1) + (a2 + a3);
        sc += __shfl_xor(sc, 1);                 // combine the two k-halves
        sc += b2i;

        const float4* gp = (const float4*)(&g_s[s][lane32 * 8]);
        float4 g0 = gp[0], g1 = gp[1];
        float tp = ((g0.x + g0.y) + (g0.z + g0.w)) + ((g1.x + g1.y) + (g1.z + g1.w));
        tp += __shfl_xor(tp, 1);
        tp += __shfl_xor(tp, 2);
        tp += __shfl_xor(tp, 4);
        tp += __shfl_xor(tp, 8);
        tp += __shfl_xor(tp, 16);

        const float beta = fmaf(tt, 19.9f, 0.1f);   // BETA_MIN + t*(BETA_MAX-BETA_MIN)
        dx  = -0.5f * beta * (xev + sc);
        dtr = -0.5f * beta * (16.0f + tp);
    };

    const float t_lo = 1e-3f;
    const float dt   = (1.0f - 1e-3f) / (float)(Tn - 1);

    for (int j = 0; j < Tn - 1; ++j) {
        const float t0 = fmaf((float)j,     dt, t_lo);
        const float t1 = fmaf((float)(j+1), dt, t_lo);
        const float hh = t1 - t0;
        float k1x, k1t, k2x, k2t, k3x, k3t, k4x, k4t;
        Feval(x,                       t0,             k1x, k1t);
        Feval(fmaf(0.5f*hh, k1x, x),   t0 + 0.5f*hh,   k2x, k2t);
        Feval(fmaf(0.5f*hh, k2x, x),   t0 + 0.5f*hh,   k3x, k3t);
        Feval(fmaf(hh,      k3x, x),   t1,             k4x, k4t);
        const float w = hh * (1.f / 6.f);
        x   = fmaf(w, k1x + 2.f*(k2x + k3x) + k4x, x);
        ldj = fmaf(w, k1t + 2.f*(k2t + k3t) + k4t, ldj);
        if (c2 == 0) xt_out[(size_t)(j + 1) * (Bn * Dn) + gs * Dn + i] = x;
    }

    if (c2 == 0)    xf_out[gs * Dn + i] = x;
    if (lane32 == 0) ldj_out[gs] = ldj;
}

extern "C" void kernel_launch(void* const* d_in, const int* in_sizes, int n_in,
                              void* d_out, int out_size, void* d_ws, size_t ws_size,
                              hipStream_t stream) {
    const float* x  = (const float*)d_in[0];
    const float* W1 = (const float*)d_in[1];
    const float* b1 = (const float*)d_in[2];
    const float* wt = (const float*)d_in[3];
    const float* W2 = (const float*)d_in[4];
    const float* b2 = (const float*)d_in[5];
    (void)in_sizes; (void)n_in; (void)out_size; (void)d_ws; (void)ws_size;
    ode_kernel<<<Bn / Sn, BLK, 0, stream>>>(x, W1, b1, wt, W2, b2, (float*)d_out);
}

// Round 2
// 348.296 us; speedup vs baseline: 1.2735x; 1.2735x over previous
//
#include <hip/hip_runtime.h>

// ODE sampler (VP-SDE probability-flow, RK4, T=50) for B=2048, D=16, H=256.
// tr(J) computed analytically: tr = -0.5*beta*(D + sum_k (1-h_k^2)*c_k),
// c_k = sum_i W1[i,k]*W2[k,i] — no JVPs.
//
// R2 changes vs R1 (which was latency-bound: occ 11.7%, 5.3e7 LDS conflicts):
//  - Sn=2 samples/block, grid=1024 -> 4 blocks/CU (16 waves/CU).
//  - W2 slices register-cached per phase-2 thread (32 VGPR) — the conflicted
//    w2t LDS reads are gone.
//  - trace via phase-1 shuffle butterfly (g_s LDS array gone).
//  - h rows chunk-padded: 8 chunks x (32+4) floats, so the 8 k-chunk readers
//    hit bank quads (c+m) mod 8 — all distinct per instruction. h writes are
//    2-way aliased = free (m136).

#define Bn 2048
#define Dn 16
#define Hn 256
#define Tn 50
#define Sn 2
#define BLK 256
#define CHW 36            // floats per k-chunk: 32 + 4 pad
#define HROW (8 * CHW)    // 288 floats per sample row

__global__ __launch_bounds__(BLK, 4) void ode_kernel(
    const float* __restrict__ x_in,   // [B][D]
    const float* __restrict__ W1,     // [D][H]
    const float* __restrict__ b1v,    // [H]
    const float* __restrict__ wtv,    // [H]
    const float* __restrict__ W2,     // [H][D]
    const float* __restrict__ b2v,    // [D]
    float* __restrict__ out)          // xf[B*D] | ldjf[B] | xt[T*B*D]
{
    __shared__ __align__(16) float h_s[Sn][HROW];   // activations, chunk-padded
    __shared__ __align__(16) float xe[Sn][Dn];      // current eval point
    __shared__ __align__(16) float tr_part[Sn][4];  // per-wave trace partials

    const int t = threadIdx.x;
    // phase-1 role: hidden unit k
    const int k = t;
    // phase-2 role: (sample, out dim, k-chunk)
    const int s = t >> 7;          // 0..1
    const int i = (t >> 3) & 15;   // 0..15
    const int c = t & 7;           // 0..7  (k in [c*32, c*32+32))

    // ---- one-time init ----
    float w1c[16];
    #pragma unroll
    for (int ii = 0; ii < 16; ++ii) w1c[ii] = W1[ii * Hn + k];

    float ck = 0.f;
    {
        const float4* w2row = (const float4*)(W2 + k * Dn);
        float4 r0 = w2row[0], r1 = w2row[1], r2 = w2row[2], r3 = w2row[3];
        const float w2r[16] = { r0.x, r0.y, r0.z, r0.w, r1.x, r1.y, r1.z, r1.w,
                                r2.x, r2.y, r2.z, r2.w, r3.x, r3.y, r3.z, r3.w };
        #pragma unroll
        for (int ii = 0; ii < 16; ++ii) ck = fmaf(w1c[ii], w2r[ii], ck);
    }

    // phase-2 W2 slice: W2[c*32 + j][i], j = 0..31 (fixed for whole kernel)
    float w2s[32];
    #pragma unroll
    for (int j = 0; j < 32; ++j) w2s[j] = W2[(c * 32 + j) * Dn + i];

    const float b1k = b1v[k];
    const float wtk = wtv[k];
    const float b2i = b2v[i];

    const int gs = blockIdx.x * Sn + s;          // global sample id
    float x   = x_in[gs * Dn + i];               // state component (s,i)
    float ldj = 0.f;

    float* xf_out  = out;
    float* ldj_out = out + (size_t)Bn * Dn;
    float* xt_out  = out + (size_t)Bn * Dn + Bn;

    if (c == 0) xt_out[gs * Dn + i] = x;         // xt[0] = initial x

    const int wv   = t >> 6;                     // wave id in block
    const int woff = (k >> 5) * CHW + (k & 31);  // chunk-padded h index

    auto Feval = [&](float xev, float tt, float& dx, float& dtr) {
        if (c == 0) xe[s][i] = xev;
        __syncthreads();

        // ---- phase 1: h_k for both samples + trace butterfly ----
        const float pre = fmaf(tt, wtk, b1k);
        const float4* x0p = (const float4*)(&xe[0][0]);   // uniform: broadcast
        const float4* x1p = (const float4*)(&xe[1][0]);
        float4 A0 = x0p[0], A1 = x0p[1], A2 = x0p[2], A3 = x0p[3];
        float4 B0 = x1p[0], B1 = x1p[1], B2 = x1p[2], B3 = x1p[3];

        float ua = pre, ub = 0.f;                 // 2 chains per sample for ILP
        ua = fmaf(A0.x, w1c[0],  ua); ub = fmaf(A2.x, w1c[8],  ub);
        ua = fmaf(A0.y, w1c[1],  ua); ub = fmaf(A2.y, w1c[9],  ub);
        ua = fmaf(A0.z, w1c[2],  ua); ub = fmaf(A2.z, w1c[10], ub);
        ua = fmaf(A0.w, w1c[3],  ua); ub = fmaf(A2.w, w1c[11], ub);
        ua = fmaf(A1.x, w1c[4],  ua); ub = fmaf(A3.x, w1c[12], ub);
        ua = fmaf(A1.y, w1c[5],  ua); ub = fmaf(A3.y, w1c[13], ub);
        ua = fmaf(A1.z, w1c[6],  ua); ub = fmaf(A3.z, w1c[14], ub);
        ua = fmaf(A1.w, w1c[7],  ua); ub = fmaf(A3.w, w1c[15], ub);
        float va = pre, vb = 0.f;
        va = fmaf(B0.x, w1c[0],  va); vb = fmaf(B2.x, w1c[8],  vb);
        va = fmaf(B0.y, w1c[1],  va); vb = fmaf(B2.y, w1c[9],  vb);
        va = fmaf(B0.z, w1c[2],  va); vb = fmaf(B2.z, w1c[10], vb);
        va = fmaf(B0.w, w1c[3],  va); vb = fmaf(B2.w, w1c[11], vb);
        va = fmaf(B1.x, w1c[4],  va); vb = fmaf(B3.x, w1c[12], vb);
        va = fmaf(B1.y, w1c[5],  va); vb = fmaf(B3.y, w1c[13], vb);
        va = fmaf(B1.z, w1c[6],  va); vb = fmaf(B3.z, w1c[14], vb);
        va = fmaf(B1.w, w1c[7],  va); vb = fmaf(B3.w, w1c[15], vb);
        const float u0 = ua + ub;
        const float u1 = va + vb;

        // tanh(u) = 1 - 2/(e^{2u}+1); e overflow -> inf -> h=1 (correct sat.)
        const float e0 = __expf(2.f * u0);
        const float e1 = __expf(2.f * u1);
        const float h0 = fmaf(-2.f, __builtin_amdgcn_rcpf(e0 + 1.f), 1.f);
        const float h1 = fmaf(-2.f, __builtin_amdgcn_rcpf(e1 + 1.f), 1.f);
        h_s[0][woff] = h0;
        h_s[1][woff] = h1;

        float g0 = fmaf(-h0, h0 * ck, ck);        // (1-h0^2)*ck
        float g1 = fmaf(-h1, h1 * ck, ck);
        #pragma unroll
        for (int off = 1; off < 64; off <<= 1) {
            g0 += __shfl_xor(g0, off);
            g1 += __shfl_xor(g1, off);
        }
        if ((t & 63) == 0) { tr_part[0][wv] = g0; tr_part[1][wv] = g1; }
        __syncthreads();

        // ---- phase 2: score dot (h broadcast reads, W2 in regs) ----
        const float4* hrow = (const float4*)(&h_s[s][0]);
        float a0 = 0.f, a1 = 0.f, a2 = 0.f, a3 = 0.f;
        #pragma unroll
        for (int m = 0; m < 8; ++m) {
            float4 hv = hrow[c * 9 + m];          // quad (c+m)&7: conflict-free
            a0 = fmaf(hv.x, w2s[m * 4 + 0], a0);
            a1 = fmaf(hv.y, w2s[m * 4 + 1], a1);
            a2 = fmaf(hv.z, w2s[m * 4 + 2], a2);
            a3 = fmaf(hv.w, w2s[m * 4 + 3], a3);
        }
        float sc = (a0 + a1) + (a2 + a3);
        sc += __shfl_xor(sc, 1);
        sc += __shfl_xor(sc, 2);
        sc += __shfl_xor(sc, 4);                  // all 8 c-lanes hold full sum
        sc += b2i;

        const float4 tp = *(const float4*)(&tr_part[s][0]);
        const float tr  = (tp.x + tp.y) + (tp.z + tp.w);

        const float beta = fmaf(tt, 19.9f, 0.1f);
        dx  = -0.5f * beta * (xev + sc);
        dtr = -0.5f * beta * (16.f + tr);
    };

    const float t_lo = 1e-3f;
    const float dt   = (1.0f - 1e-3f) / (float)(Tn - 1);

    for (int j = 0; j < Tn - 1; ++j) {
        const float t0 = fmaf((float)j,       dt, t_lo);
        const float t1 = fmaf((float)(j + 1), dt, t_lo);
        const float hh = t1 - t0;
        float k1x, k1t, k2x, k2t, k3x, k3t, k4x, k4t;
        Feval(x,                     t0,           k1x, k1t);
        Feval(fmaf(0.5f*hh, k1x, x), t0 + 0.5f*hh, k2x, k2t);
        Feval(fmaf(0.5f*hh, k2x, x), t0 + 0.5f*hh, k3x, k3t);
        Feval(fmaf(hh,      k3x, x), t1,           k4x, k4t);
        const float w = hh * (1.f / 6.f);
        x   = fmaf(w, k1x + 2.f*(k2x + k3x) + k4x, x);
        ldj = fmaf(w, k1t + 2.f*(k2t + k3t) + k4t, ldj);
        if (c == 0) xt_out[(size_t)(j + 1) * (Bn * Dn) + gs * Dn + i] = x;
    }

    if (c == 0)             xf_out[gs * Dn + i] = x;
    if ((t & 127) == 0)     ldj_out[gs] = ldj;
}

extern "C" void kernel_launch(void* const* d_in, const int* in_sizes, int n_in,
                              void* d_out, int out_size, void* d_ws, size_t ws_size,
                              hipStream_t stream) {
    const float* x  = (const float*)d_in[0];
    const float* W1 = (const float*)d_in[1];
    const float* b1 = (const float*)d_in[2];
    const float* wt = (const float*)d_in[3];
    const float* W2 = (const float*)d_in[4];
    const float* b2 = (const float*)d_in[5];
    (void)in_sizes; (void)n_in; (void)out_size; (void)d_ws; (void)ws_size;
    ode_kernel<<<Bn / Sn, BLK, 0, stream>>>(x, W1, b1, wt, W2, b2, (float*)d_out);
}

// Round 3
// 231.524 us; speedup vs baseline: 1.9158x; 1.5044x over previous
//
#include <hip/hip_runtime.h>

// ODE sampler (VP-SDE probability-flow, RK4, T=50) for B=2048, D=16, H=256.
// tr(J) analytic: tr = -0.5*beta*(D + sum_k (1-h_k^2)*c_k), c_k = sum_i W1[i,k]W2[k,i].
//
// R3: wave-synchronous — ONE WAVE PER SAMPLE, zero __syncthreads.
//  R2 was barrier-bound (392 block barriers; VALUBusy 51%, dur 319us).
//  - lane L: phase-1 owns k = 4L..4L+3 (W1 cols + c_k in regs, h via b128 LDS write)
//            phase-2 owns (i = L>>2, chunk c = L&3) (W2 slice in 64 regs)
//  - phase1->phase2 handoff via same-wave LDS (in-order DS pipe; compiler fence only)
//  - trace: 6-level shuffle butterfly (one sample/wave), overlaps phase-2 dot
//  - h row chunk-padded 4 x 18 float4s: phase-2 reads are 4-address 16-lane
//    broadcasts at distinct bank quads (2c+m mod 8) — conflict-free.

#define Bn 2048
#define Dn 16
#define Hn 256
#define Tn 50
#define WPB 4              // waves (= samples) per block
#define BLK (WPB * 64)
#define CQ 18              // float4s per k-chunk: 16 data + 2 pad
#define HROWQ (4 * CQ)     // 72 float4s per sample row

__global__ __launch_bounds__(BLK, 2) void ode_kernel(
    const float* __restrict__ x_in,   // [B][D]
    const float* __restrict__ W1,     // [D][H]
    const float* __restrict__ b1v,    // [H]
    const float* __restrict__ wtv,    // [H]
    const float* __restrict__ W2,     // [H][D]
    const float* __restrict__ b2v,    // [D]
    float* __restrict__ out)          // xf[B*D] | ldjf[B] | xt[T*B*D]
{
    __shared__ __align__(16) float4 h_q[WPB][HROWQ];
    __shared__ __align__(16) float  xe[WPB][16];

    const int t  = threadIdx.x;
    const int w  = t >> 6;            // wave id = sample in block
    const int L  = t & 63;
    const int i  = L >> 2;            // phase-2 output dim
    const int c  = L & 3;             // phase-2 k-chunk (64 k's)
    const int gs = blockIdx.x * WPB + w;
    const int k0 = 4 * L;             // phase-1: first of this lane's 4 k's

    // ---- one-time init: all weights into registers ----
    float4 w1c[16];                   // w1c[ii] = W1[ii][k0..k0+3]
    #pragma unroll
    for (int ii = 0; ii < 16; ++ii)
        w1c[ii] = *(const float4*)(W1 + ii * Hn + k0);

    float w2s[64];                    // w2s[j] = W2[64c + j][i]
    #pragma unroll
    for (int j = 0; j < 64; ++j)
        w2s[j] = W2[(64 * c + j) * Dn + i];

    float4 ck4 = {0.f, 0.f, 0.f, 0.f};  // c_k for the lane's 4 k's
    #pragma unroll
    for (int ii = 0; ii < 16; ++ii) {
        ck4.x = fmaf(w1c[ii].x, W2[(k0 + 0) * Dn + ii], ck4.x);
        ck4.y = fmaf(w1c[ii].y, W2[(k0 + 1) * Dn + ii], ck4.y);
        ck4.z = fmaf(w1c[ii].z, W2[(k0 + 2) * Dn + ii], ck4.z);
        ck4.w = fmaf(w1c[ii].w, W2[(k0 + 3) * Dn + ii], ck4.w);
    }

    const float4 b1k = *(const float4*)(b1v + k0);
    const float4 wtk = *(const float4*)(wtv + k0);
    const float  b2i = b2v[i];

    float x   = x_in[gs * Dn + i];    // lane state: x_i (replicated over c)
    float ldj = 0.f;

    float* xf_out  = out;
    float* ldj_out = out + (size_t)Bn * Dn;
    float* xt_out  = out + (size_t)Bn * Dn + Bn;

    if (c == 0) xt_out[gs * Dn + i] = x;   // xt[0] = initial state

    auto Feval = [&](float xev, float tt, float& dx, float& dtr) {
        if (c == 0) xe[w][i] = xev;
        asm volatile("" ::: "memory");     // order LDS write before reads (same wave)

        // ---- phase 1: h for the lane's 4 k's ----
        const float4 X0 = *(const float4*)(&xe[w][0]);   // wave-uniform broadcast
        const float4 X1 = *(const float4*)(&xe[w][4]);
        const float4 X2 = *(const float4*)(&xe[w][8]);
        const float4 X3 = *(const float4*)(&xe[w][12]);
        const float xv[16] = { X0.x, X0.y, X0.z, X0.w, X1.x, X1.y, X1.z, X1.w,
                               X2.x, X2.y, X2.z, X2.w, X3.x, X3.y, X3.z, X3.w };
        float u0 = fmaf(tt, wtk.x, b1k.x);
        float u1 = fmaf(tt, wtk.y, b1k.y);
        float u2 = fmaf(tt, wtk.z, b1k.z);
        float u3 = fmaf(tt, wtk.w, b1k.w);
        #pragma unroll
        for (int ii = 0; ii < 16; ++ii) {
            u0 = fmaf(xv[ii], w1c[ii].x, u0);
            u1 = fmaf(xv[ii], w1c[ii].y, u1);
            u2 = fmaf(xv[ii], w1c[ii].z, u2);
            u3 = fmaf(xv[ii], w1c[ii].w, u3);
        }
        // tanh(u) = 1 - 2/(e^{2u}+1); exp overflow/underflow saturates correctly
        const float h0 = fmaf(-2.f, __builtin_amdgcn_rcpf(__expf(2.f * u0) + 1.f), 1.f);
        const float h1 = fmaf(-2.f, __builtin_amdgcn_rcpf(__expf(2.f * u1) + 1.f), 1.f);
        const float h2 = fmaf(-2.f, __builtin_amdgcn_rcpf(__expf(2.f * u2) + 1.f), 1.f);
        const float h3 = fmaf(-2.f, __builtin_amdgcn_rcpf(__expf(2.f * u3) + 1.f), 1.f);
        const float4 hv4 = { h0, h1, h2, h3 };
        h_q[w][CQ * (L >> 4) + (L & 15)] = hv4;   // bank-balanced b128 write

        // trace partial: sum_j (1-h_j^2)*ck_j
        float g = (fmaf(-h0 * h0, ck4.x, ck4.x) + fmaf(-h1 * h1, ck4.y, ck4.y))
                + (fmaf(-h2 * h2, ck4.z, ck4.z) + fmaf(-h3 * h3, ck4.w, ck4.w));

        asm volatile("" ::: "memory");     // order h write before phase-2 reads

        // ---- phase 2: score dot over chunk c (h broadcast, W2 in regs) ----
        const float4* hrow = &h_q[w][CQ * c];
        float a0 = 0.f, a1 = 0.f, a2 = 0.f, a3 = 0.f;
        #pragma unroll
        for (int m = 0; m < 16; ++m) {
            const float4 hv = hrow[m];
            a0 = fmaf(hv.x, w2s[4 * m + 0], a0);
            a1 = fmaf(hv.y, w2s[4 * m + 1], a1);
            a2 = fmaf(hv.z, w2s[4 * m + 2], a2);
            a3 = fmaf(hv.w, w2s[4 * m + 3], a3);
        }
        float sc = (a0 + a1) + (a2 + a3);
        sc += __shfl_xor(sc, 1);
        sc += __shfl_xor(sc, 2);           // all 4 c-lanes hold full sc_i
        sc += b2i;

        #pragma unroll
        for (int off = 1; off < 64; off <<= 1)   // trace: full-wave butterfly
            g += __shfl_xor(g, off);

        const float beta = fmaf(tt, 19.9f, 0.1f);
        dx  = -0.5f * beta * (xev + sc);
        dtr = -0.5f * beta * (16.f + g);
    };

    const float t_lo = 1e-3f;
    const float dt   = (1.0f - 1e-3f) / (float)(Tn - 1);

    for (int j = 0; j < Tn - 1; ++j) {
        const float t0 = fmaf((float)j,       dt, t_lo);
        const float t1 = fmaf((float)(j + 1), dt, t_lo);
        const float hh = t1 - t0;
        float k1x, k1t, k2x, k2t, k3x, k3t, k4x, k4t;
        Feval(x,                     t0,           k1x, k1t);
        Feval(fmaf(0.5f*hh, k1x, x), t0 + 0.5f*hh, k2x, k2t);
        Feval(fmaf(0.5f*hh, k2x, x), t0 + 0.5f*hh, k3x, k3t);
        Feval(fmaf(hh,      k3x, x), t1,           k4x, k4t);
        const float wq = hh * (1.f / 6.f);
        x   = fmaf(wq, k1x + 2.f*(k2x + k3x) + k4x, x);
        ldj = fmaf(wq, k1t + 2.f*(k2t + k3t) + k4t, ldj);
        if (c == 0) xt_out[(size_t)(j + 1) * (Bn * Dn) + gs * Dn + i] = x;
    }

    if (c == 0) xf_out[gs * Dn + i] = x;
    if (L == 0) ldj_out[gs] = ldj;
}

extern "C" void kernel_launch(void* const* d_in, const int* in_sizes, int n_in,
                              void* d_out, int out_size, void* d_ws, size_t ws_size,
                              hipStream_t stream) {
    const float* x  = (const float*)d_in[0];
    const float* W1 = (const float*)d_in[1];
    const float* b1 = (const float*)d_in[2];
    const float* wt = (const float*)d_in[3];
    const float* W2 = (const float*)d_in[4];
    const float* b2 = (const float*)d_in[5];
    (void)in_sizes; (void)n_in; (void)out_size; (void)d_ws; (void)ws_size;
    ode_kernel<<<Bn / WPB, BLK, 0, stream>>>(x, W1, b1, wt, W2, b2, (float*)d_out);
}

// Round 4
// 199.598 us; speedup vs baseline: 2.2222x; 1.1600x over previous
//
#include <hip/hip_runtime.h>
#include <stdint.h>

// ODE sampler (VP-SDE probability-flow, RK4, T=50) for B=2048, D=16, H=256.
// tr(J) analytic: tr = -0.5*beta*(D + sum_k (1-h_k^2)*c_k).
//
// R4 vs R3 (192us kernel, VALUBusy 70%, ~2x instr bloat suspected from
// non-resident weight arrays at VGPR=108):
//  - dots via v_dot2_f32_f16 (2 MAC/instr, fp32 acc): 128 -> 64 dot instrs
//  - weights as packed f16 pairs: 128 -> 64 weight VGPRs (forces residency)
//  - h handoff in LDS as packed f16: 16 -> 4 b128 reads per Feval
//  - trace/ldj reduction deferred out of the loop (per-lane partials; one
//    butterfly at the end) — the trace never feeds back into x.
// Wave-synchronous (one wave per sample), zero __syncthreads, kept from R3.

typedef _Float16 f16x2 __attribute__((ext_vector_type(2)));

#if defined(__has_builtin)
#if __has_builtin(__builtin_amdgcn_fdot2)
#define HAVE_FDOT2 1
#endif
#endif

__device__ __forceinline__ float fdot2f(f16x2 a, f16x2 b, float c) {
#ifdef HAVE_FDOT2
    return __builtin_amdgcn_fdot2(a, b, c, false);
#else
    return fmaf((float)a.y, (float)b.y, fmaf((float)a.x, (float)b.x, c));
#endif
}

__device__ __forceinline__ uint32_t pk(float a, float b) {
    f16x2 v; v.x = (_Float16)a; v.y = (_Float16)b;   // RNE casts
    return __builtin_bit_cast(uint32_t, v);
}
__device__ __forceinline__ f16x2 upk(uint32_t u) {
    return __builtin_bit_cast(f16x2, u);
}

#define Bn 2048
#define Dn 16
#define Hn 256
#define Tn 50
#define WPB 4
#define BLK (WPB * 64)
#define CHD 20                 // dwords per k-chunk: 16 data + 4 pad

__global__ __launch_bounds__(BLK, 2) void ode_kernel(
    const float* __restrict__ x_in,   // [B][D]
    const float* __restrict__ W1,     // [D][H]
    const float* __restrict__ b1v,    // [H]
    const float* __restrict__ wtv,    // [H]
    const float* __restrict__ W2,     // [H][D]
    const float* __restrict__ b2v,    // [D]
    float* __restrict__ out)          // xf[B*D] | ldjf[B] | xt[T*B*D]
{
    __shared__ __align__(16) uint32_t h_lds[WPB][8 * CHD];  // h, f16-pair packed
    __shared__ __align__(16) uint32_t xe[WPB][12];          // eval point, packed

    const int t  = threadIdx.x;
    const int w  = t >> 6;            // wave = sample in block
    const int L  = t & 63;
    const int g8 = L >> 3;            // i-pair group 0..7
    const int c  = L & 7;             // k-chunk 0..7 (32 k's each)
    const int ia = 2 * g8, ib = ia + 1;
    const int k0 = 4 * L;             // phase-1: this lane's 4 hidden units
    const int gs = blockIdx.x * WPB + w;

    // ---- one-time init: weights packed to f16 registers ----
    f16x2 w1p[4][8];                  // [q][j] = {W1[2j][k0+q], W1[2j+1][k0+q]}
    float b1k[4], wtk[4], ck[4];
    #pragma unroll
    for (int q = 0; q < 4; ++q) {
        #pragma unroll
        for (int j = 0; j < 8; ++j) {
            f16x2 v;
            v.x = (_Float16)W1[(2 * j)     * Hn + k0 + q];
            v.y = (_Float16)W1[(2 * j + 1) * Hn + k0 + q];
            w1p[q][j] = v;
        }
        b1k[q] = b1v[k0 + q];
        wtk[q] = wtv[k0 + q];
        float s = 0.f;
        #pragma unroll
        for (int ii = 0; ii < 16; ++ii)
            s = fmaf(W1[ii * Hn + k0 + q], W2[(k0 + q) * Dn + ii], s);
        ck[q] = s;
    }
    f16x2 w2a[16], w2b[16];           // [m] = {W2[32c+2m][i], W2[32c+2m+1][i]}
    #pragma unroll
    for (int m = 0; m < 16; ++m) {
        f16x2 va, vb;
        va.x = (_Float16)W2[(32 * c + 2 * m)     * Dn + ia];
        va.y = (_Float16)W2[(32 * c + 2 * m + 1) * Dn + ia];
        vb.x = (_Float16)W2[(32 * c + 2 * m)     * Dn + ib];
        vb.y = (_Float16)W2[(32 * c + 2 * m + 1) * Dn + ib];
        w2a[m] = va; w2b[m] = vb;
    }
    const float b2a = b2v[ia], b2b = b2v[ib];

    float xa = x_in[gs * Dn + ia];
    float xb = x_in[gs * Dn + ib];
    float ldjl = 0.f;                 // per-lane ldj partial (deferred reduce)

    float* xf_out  = out;
    float* ldj_out = out + (size_t)Bn * Dn;
    float* xt_ptr  = out + (size_t)Bn * Dn + Bn + gs * Dn + ia;  // xt[0] slot

    if (c == 0) *(float2*)xt_ptr = make_float2(xa, xb);
    xt_ptr += Bn * Dn;

    auto Feval = [&](float xeva, float xevb, float tt, float wgt,
                     float& dxa, float& dxb) {
        if (c == 0) xe[w][g8] = pk(xeva, xevb);
        asm volatile("" ::: "memory");

        // ---- phase 1: u for this lane's 4 k's (f16 dot2, fp32 acc) ----
        const uint4 xl0 = *(const uint4*)&xe[w][0];
        const uint4 xl1 = *(const uint4*)&xe[w][4];
        const f16x2 xp[8] = { upk(xl0.x), upk(xl0.y), upk(xl0.z), upk(xl0.w),
                              upk(xl1.x), upk(xl1.y), upk(xl1.z), upk(xl1.w) };
        float u0 = fmaf(tt, wtk[0], b1k[0]);
        float u1 = fmaf(tt, wtk[1], b1k[1]);
        float u2 = fmaf(tt, wtk[2], b1k[2]);
        float u3 = fmaf(tt, wtk[3], b1k[3]);
        #pragma unroll
        for (int j = 0; j < 8; ++j) {
            u0 = fdot2f(xp[j], w1p[0][j], u0);
            u1 = fdot2f(xp[j], w1p[1][j], u1);
            u2 = fdot2f(xp[j], w1p[2][j], u2);
            u3 = fdot2f(xp[j], w1p[3][j], u3);
        }
        // tanh(u) = 1 - 2/(e^{2u}+1); exp over/underflow saturates correctly
        const float h0 = fmaf(-2.f, __builtin_amdgcn_rcpf(__expf(2.f * u0) + 1.f), 1.f);
        const float h1 = fmaf(-2.f, __builtin_amdgcn_rcpf(__expf(2.f * u1) + 1.f), 1.f);
        const float h2 = fmaf(-2.f, __builtin_amdgcn_rcpf(__expf(2.f * u2) + 1.f), 1.f);
        const float h3 = fmaf(-2.f, __builtin_amdgcn_rcpf(__expf(2.f * u3) + 1.f), 1.f);

        // trace partial for own k's + deferred beta-weighted ldj accumulation
        const float gl = (fmaf(-h0 * h0, ck[0], ck[0]) + fmaf(-h1 * h1, ck[1], ck[1]))
                       + (fmaf(-h2 * h2, ck[2], ck[2]) + fmaf(-h3 * h3, ck[3], ck[3]));
        const float beta = fmaf(tt, 19.9f, 0.1f);
        const float nhb  = -0.5f * beta;
        ldjl = fmaf(wgt * nhb, 0.25f + gl, ldjl);   // 16/64 = 0.25 per lane

        // pack h (f16 pairs) and hand off via same-wave LDS
        *(uint2*)&h_lds[w][CHD * g8 + 2 * c] =
            make_uint2(pk(h0, h1), pk(h2, h3));
        asm volatile("" ::: "memory");

        // ---- phase 2: score for (ia, ib) over k-chunk c ----
        float sa0 = 0.f, sa1 = 0.f, sb0 = 0.f, sb1 = 0.f;
        #pragma unroll
        for (int mq = 0; mq < 4; ++mq) {
            const uint4 hv = *(const uint4*)&h_lds[w][CHD * c + 4 * mq];
            const f16x2 p0 = upk(hv.x), p1 = upk(hv.y), p2 = upk(hv.z), p3 = upk(hv.w);
            sa0 = fdot2f(p0, w2a[4 * mq + 0], sa0);
            sb0 = fdot2f(p0, w2b[4 * mq + 0], sb0);
            sa1 = fdot2f(p1, w2a[4 * mq + 1], sa1);
            sb1 = fdot2f(p1, w2b[4 * mq + 1], sb1);
            sa0 = fdot2f(p2, w2a[4 * mq + 2], sa0);
            sb0 = fdot2f(p2, w2b[4 * mq + 2], sb0);
            sa1 = fdot2f(p3, w2a[4 * mq + 3], sa1);
            sb1 = fdot2f(p3, w2b[4 * mq + 3], sb1);
        }
        float sca = sa0 + sa1, scb = sb0 + sb1;
        sca += __shfl_xor(sca, 1);  scb += __shfl_xor(scb, 1);
        sca += __shfl_xor(sca, 2);  scb += __shfl_xor(scb, 2);
        sca += __shfl_xor(sca, 4);  scb += __shfl_xor(scb, 4);
        sca += b2a;  scb += b2b;

        dxa = nhb * (xeva + sca);
        dxb = nhb * (xevb + scb);
    };

    const float t_lo = 1e-3f;
    const float dt   = (1.0f - 1e-3f) / (float)(Tn - 1);

    for (int j = 0; j < Tn - 1; ++j) {
        const float t0 = fmaf((float)j,       dt, t_lo);
        const float t1 = fmaf((float)(j + 1), dt, t_lo);
        const float hh = t1 - t0;
        const float w1w = hh * (1.f / 6.f);
        const float w2w = hh * (2.f / 6.f);
        float k1a, k1b, k2a, k2b, k3a, k3b, k4a, k4b;
        Feval(xa, xb, t0, w1w, k1a, k1b);
        Feval(fmaf(0.5f * hh, k1a, xa), fmaf(0.5f * hh, k1b, xb),
              t0 + 0.5f * hh, w2w, k2a, k2b);
        Feval(fmaf(0.5f * hh, k2a, xa), fmaf(0.5f * hh, k2b, xb),
              t0 + 0.5f * hh, w2w, k3a, k3b);
        Feval(fmaf(hh, k3a, xa), fmaf(hh, k3b, xb),
              t1, w1w, k4a, k4b);
        xa = fmaf(w1w, k1a + 2.f * (k2a + k3a) + k4a, xa);
        xb = fmaf(w1w, k1b + 2.f * (k2b + k3b) + k4b, xb);
        if (c == 0) *(float2*)xt_ptr = make_float2(xa, xb);
        xt_ptr += Bn * Dn;
    }

    if (c == 0) *(float2*)(xf_out + gs * Dn + ia) = make_float2(xa, xb);

    // deferred ldj reduction: one butterfly for the whole kernel
    #pragma unroll
    for (int off = 1; off < 64; off <<= 1)
        ldjl += __shfl_xor(ldjl, off);
    if (L == 0) ldj_out[gs] = ldjl;
}

extern "C" void kernel_launch(void* const* d_in, const int* in_sizes, int n_in,
                              void* d_out, int out_size, void* d_ws, size_t ws_size,
                              hipStream_t stream) {
    const float* x  = (const float*)d_in[0];
    const float* W1 = (const float*)d_in[1];
    const float* b1 = (const float*)d_in[2];
    const float* wt = (const float*)d_in[3];
    const float* W2 = (const float*)d_in[4];
    const float* b2 = (const float*)d_in[5];
    (void)in_sizes; (void)n_in; (void)out_size; (void)d_ws; (void)ws_size;
    ode_kernel<<<Bn / WPB, BLK, 0, stream>>>(x, W1, b1, wt, W2, b2, (float*)d_out);
}